// Round 7
// baseline (294.165 us; speedup 1.0000x reference)
//
#include <hip/hip_runtime.h>
#include <hip/hip_bf16.h>
#include <climits>
#include <cstdint>
#include <cfloat>

#define NROWS   524288
#define KDIM    128
#define NGRAPH  64
#define NSTROKE 8192
#define EPSF    1e-5f

typedef __bf16 bf16x8 __attribute__((ext_vector_type(8)));
typedef float  f32x4  __attribute__((ext_vector_type(4)));

// ws layout (bytes)
#define WT_OFF    0                         // ushort bf16 Wt[256][128] (col-major)
#define CSUM_OFF  65536                     // float[256]
#define CSQ_OFF   66560                     // float[256]
#define ST_OFF    67584                     // int [8192][128] stroke max (int-key)
#define GT_OFF    (ST_OFF + NSTROKE*KDIM*4) // int [64][128] graph max (int-key)

__device__ __forceinline__ unsigned short f2bf(float f) {
  unsigned int u = __float_as_uint(f);
  u += 0x7fffu + ((u >> 16) & 1u);   // RNE
  return (unsigned short)(u >> 16);
}
// order-preserving float<->int key (for atomicMax)
__device__ __forceinline__ int fkey(float f) {
  int b = __float_as_int(f);
  return b >= 0 ? b : (b ^ 0x7fffffff);
}
__device__ __forceinline__ float fdec(int k) {
  int b = k >= 0 ? k : (k ^ 0x7fffffff);
  return __int_as_float(b);
}
__device__ __forceinline__ bf16x8 cvt8(f32x4 a, f32x4 b) {
  bf16x8 r;
  r[0] = (__bf16)a[0]; r[1] = (__bf16)a[1]; r[2] = (__bf16)a[2]; r[3] = (__bf16)a[3];
  r[4] = (__bf16)b[0]; r[5] = (__bf16)b[1]; r[6] = (__bf16)b[2]; r[7] = (__bf16)b[3];
  return r;
}

// ---------------- init: weights -> bf16 col-major; clear sums + max tables ----
__global__ void k_init(const float* __restrict__ Wmax, const float* __restrict__ Wsk,
                       unsigned char* __restrict__ ws) {
  unsigned short* wt = (unsigned short*)(ws + WT_OFF);
  float* csum = (float*)(ws + CSUM_OFF);
  float* csq  = (float*)(ws + CSQ_OFF);
  int* st = (int*)(ws + ST_OFF);
  int* gt = (int*)(ws + GT_OFF);
  int i = blockIdx.x * blockDim.x + threadIdx.x;
  const int total = NSTROKE * KDIM;   // 1048576
  for (; i < total; i += gridDim.x * blockDim.x) {
    st[i] = INT_MIN;
    if (i < NGRAPH * KDIM) gt[i] = INT_MIN;
    if (i < 256) { csum[i] = 0.f; csq[i] = 0.f; }
    if (i < 256 * KDIM) {
      int c = i / KDIM, k = i % KDIM;
      float w = (c < 128) ? Wsk[k * 128 + c] : Wmax[k * 128 + (c - 128)];
      wt[i] = f2bf(w);   // wt[c][k]
    }
  }
}

// ---------------- pass1: 8-wave fused GEMM, acc-direct seg-max, 1 barrier/tile -
// 512 threads = 8 waves; wave w owns cols [w*32, w*32+32) (w<4: sketch/stroke,
// w>=4: max/graph). acc[4][2] per thread; seg-max and BN sums computed straight
// from accumulators (no h LDS round trip, no scan). T14 stage split: issue
// global loads -> compute current tile -> convert+ds_write -> one barrier.
__global__ __launch_bounds__(512, 4) void k_pass1(const float* __restrict__ x,
                                                  const int* __restrict__ batch,
                                                  const int* __restrict__ stroke,
                                                  unsigned char* __restrict__ ws) {
  __shared__ __align__(16) unsigned short xs[2][64 * 128];  // 2 x 16 KB bf16, swz
  const unsigned short* wt = (const unsigned short*)(ws + WT_OFF);
  float* csum = (float*)(ws + CSUM_OFF);
  float* csq  = (float*)(ws + CSQ_OFF);
  int* st = (int*)(ws + ST_OFF);
  int* gt = (int*)(ws + GT_OFF);

  const int tid  = threadIdx.x;
  const int lane = tid & 63;
  const int w    = tid >> 6;      // wave 0..7
  const int lr   = lane & 15;
  const int lg   = lane >> 4;
  const int colbase = w * 32;     // combined column base
  const bool isS = (w < 4);
  const int* __restrict__ segp = isS ? stroke : batch;
  int* __restrict__ tab = isS ? st : gt;
  const int tcol = colbase - (isS ? 0 : 128);   // table column base

  // B fragments: lane holds Wt[col = colbase+n*16+lr][k = ks*32+lg*8 ..+7]
  bf16x8 bfrag[4][2];
#pragma unroll
  for (int ks = 0; ks < 4; ++ks)
#pragma unroll
    for (int n = 0; n < 2; ++n)
      bfrag[ks][n] = *(const bf16x8*)(wt + (colbase + n * 16 + lr) * KDIM + ks * 32 + lg * 8);

  // staging geometry: thread stages row srow, floats [su*16, su*16+16)
  const int srow = tid >> 3;
  const int su   = tid & 7;
  const int brow = blockIdx.x * 512;

  float sumn[2] = {0.f, 0.f};
  float sqn[2]  = {0.f, 0.f};
  float tmax0 = -FLT_MAX, tmax1 = -FLT_MAX;
  int   curseg = -1;

#define FLUSH()                                                               \
  if (curseg >= 0) {                                                          \
    float f0 = tmax0, f1 = tmax1;                                             \
    f0 = fmaxf(f0, __shfl_xor(f0, 16)); f0 = fmaxf(f0, __shfl_xor(f0, 32));   \
    f1 = fmaxf(f1, __shfl_xor(f1, 16)); f1 = fmaxf(f1, __shfl_xor(f1, 32));   \
    if (lg == 0) {                                                            \
      atomicMax(&tab[curseg * KDIM + tcol + lr],      fkey(f0));              \
      atomicMax(&tab[curseg * KDIM + tcol + 16 + lr], fkey(f1));              \
    }                                                                         \
  }

#define STAGE_LD(T)                                                           \
  {                                                                           \
    const float* src_ = x + (size_t)(brow + (T) * 64 + srow) * KDIM + su * 16;\
    ld0 = *(const f32x4*)(src_);                                              \
    ld1 = *(const f32x4*)(src_ + 4);                                          \
    ld2 = *(const f32x4*)(src_ + 8);                                          \
    ld3 = *(const f32x4*)(src_ + 12);                                         \
  }
#define STAGE_WR(P)                                                           \
  {                                                                           \
    unsigned short* xb_ = xs[P];                                              \
    int kg0 = su * 2;                                                         \
    *(bf16x8*)(xb_ + srow * KDIM + (((kg0    ) ^ (srow & 7)) << 3)) = cvt8(ld0, ld1); \
    *(bf16x8*)(xb_ + srow * KDIM + (((kg0 + 1) ^ (srow & 7)) << 3)) = cvt8(ld2, ld3); \
  }

  f32x4 ld0, ld1, ld2, ld3;
  STAGE_LD(0);
  int segNext = segp[brow + lane];
  STAGE_WR(0);
  __syncthreads();

  for (int t = 0; t < 8; ++t) {
    const unsigned short* xb = xs[t & 1];
    const int segLane = segNext;

    // ---- issue next tile's global loads (hide under compute) ----
    if (t < 7) {
      STAGE_LD(t + 1);
      segNext = segp[brow + (t + 1) * 64 + lane];
    }

    // ---- MFMA: 64 rows x 32 cols ----
    f32x4 acc[4][2];
#pragma unroll
    for (int m = 0; m < 4; ++m)
#pragma unroll
      for (int n = 0; n < 2; ++n) { f32x4 z = {0.f, 0.f, 0.f, 0.f}; acc[m][n] = z; }

#pragma unroll
    for (int ks = 0; ks < 4; ++ks) {
      bf16x8 af[4];
#pragma unroll
      for (int m = 0; m < 4; ++m) {
        int r  = m * 16 + lr;
        int kg = ks * 4 + lg;
        af[m] = *(const bf16x8*)(xb + r * KDIM + ((kg ^ (r & 7)) << 3));
      }
#pragma unroll
      for (int m = 0; m < 4; ++m) {
        acc[m][0] = __builtin_amdgcn_mfma_f32_16x16x32_bf16(af[m], bfrag[ks][0], acc[m][0], 0, 0, 0);
        acc[m][1] = __builtin_amdgcn_mfma_f32_16x16x32_bf16(af[m], bfrag[ks][1], acc[m][1], 0, 0, 0);
      }
    }

    // ---- BN sums + tile col-max straight from accumulators ----
    float s0 = 0.f, q0 = 0.f, s1 = 0.f, q1 = 0.f;
    float t0 = -FLT_MAX, t1 = -FLT_MAX;
#pragma unroll
    for (int m = 0; m < 4; ++m)
#pragma unroll
      for (int rg = 0; rg < 4; ++rg) {
        float v0 = acc[m][0][rg], v1 = acc[m][1][rg];
        s0 += v0; q0 = fmaf(v0, v0, q0); t0 = fmaxf(t0, v0);
        s1 += v1; q1 = fmaf(v1, v1, q1); t1 = fmaxf(t1, v1);
      }
    sumn[0] += s0; sqn[0] += q0; sumn[1] += s1; sqn[1] += q1;

    // ---- segment max from accumulators (per-wave, no LDS) ----
    {
      int pv = __shfl_up(segLane, 1);
      unsigned long long mask = __ballot(lane > 0 && pv != segLane);
      if (mask == 0ull) {
        int seg0 = __shfl(segLane, 0);
        if (seg0 != curseg) {
          FLUSH();
          curseg = seg0; tmax0 = t0; tmax1 = t1;
        } else {
          tmax0 = fmaxf(tmax0, t0); tmax1 = fmaxf(tmax1, t1);
        }
      } else {
        unsigned long long rem = mask;
        int a = 0;
        while (true) {
          int b = rem ? (int)__builtin_ctzll(rem) : 64;
          int segr = __shfl(segLane, a);
          float r0 = -FLT_MAX, r1 = -FLT_MAX;
#pragma unroll
          for (int m = 0; m < 4; ++m)
#pragma unroll
            for (int rg = 0; rg < 4; ++rg) {
              int row = m * 16 + lg * 4 + rg;
              bool in = (row >= a) && (row < b);
              r0 = in ? fmaxf(r0, acc[m][0][rg]) : r0;
              r1 = in ? fmaxf(r1, acc[m][1][rg]) : r1;
            }
          if (a == 0 && segr == curseg) {
            tmax0 = fmaxf(tmax0, r0); tmax1 = fmaxf(tmax1, r1);
          } else {
            FLUSH();
            curseg = segr; tmax0 = r0; tmax1 = r1;
          }
          if (b >= 64) break;
          rem &= rem - 1; a = b;
        }
      }
    }

    // ---- write next tile to LDS, single barrier ----
    if (t < 7) STAGE_WR((t + 1) & 1);
    __syncthreads();
  }

  FLUSH();   // final carried run

  // ---- BN sums: shfl-reduce over lg, one atomic per column ----
#pragma unroll
  for (int n = 0; n < 2; ++n) {
    float s = sumn[n], q = sqn[n];
    s += __shfl_xor(s, 16); s += __shfl_xor(s, 32);
    q += __shfl_xor(q, 16); q += __shfl_xor(q, 32);
    if (lg == 0) {
      atomicAdd(&csum[colbase + n * 16 + lr], s);
      atomicAdd(&csq [colbase + n * 16 + lr], q);
    }
  }
#undef FLUSH
#undef STAGE_LD
#undef STAGE_WR
}

// ---------------- out: gather + BN(affine)+ReLU on the fly + stream write ------
// (R2-exact: NT stores, unconditional pipelined gathers)
__global__ __launch_bounds__(256) void k_out(const int* __restrict__ batch,
                                             const int* __restrict__ stroke,
                                             const float* __restrict__ g_max,
                                             const float* __restrict__ be_max,
                                             const float* __restrict__ g_sk,
                                             const float* __restrict__ be_sk,
                                             const unsigned char* __restrict__ ws,
                                             float* __restrict__ out) {
  const float* csum = (const float*)(ws + CSUM_OFF);
  const float* csq  = (const float*)(ws + CSQ_OFF);
  const int* st = (const int*)(ws + ST_OFF);
  const int* gt = (const int*)(ws + GT_OFF);

  const int lane = threadIdx.x & 63;
  const int wvid = blockIdx.x * 4 + (threadIdx.x >> 6);
  const int row0 = wvid * 64;
  const bool isS = lane < 32;
  const int  cg  = (isS ? lane : lane - 32) * 4;
  const int* tab  = isS ? st : gt;
  const int* idxp = isS ? stroke : batch;
  const float* gv = isS ? g_sk : g_max;
  const float* bv = isS ? be_sk : be_max;

  const float invN = 1.0f / (float)NROWS;
  f32x4 mu, sc, bb;
#pragma unroll
  for (int j = 0; j < 4; ++j) {
    int cc = (isS ? 0 : 128) + cg + j;
    float m  = csum[cc] * invN;
    float vr = csq[cc] * invN - m * m;
    mu[j] = m;
    sc[j] = gv[cg + j] * rsqrtf(vr + EPSF);
    bb[j] = bv[cg + j];
  }

  f32x4* out4 = (f32x4*)out;
#pragma unroll 4
  for (int r = 0; r < 64; ++r) {
    int row = row0 + r;
    int seg = idxp[row];
    const int4 k4 = *(const int4*)(tab + (size_t)seg * KDIM + cg);
    f32x4 v;
    v[0] = fdec(k4.x); v[1] = fdec(k4.y); v[2] = fdec(k4.z); v[3] = fdec(k4.w);
#pragma unroll
    for (int j = 0; j < 4; ++j) v[j] = fmaxf(0.f, (v[j] - mu[j]) * sc[j] + bb[j]);
    __builtin_nontemporal_store(v, &out4[(size_t)row * 64 + lane]);
  }
}

extern "C" void kernel_launch(void* const* d_in, const int* in_sizes, int n_in,
                              void* d_out, int out_size, void* d_ws, size_t ws_size,
                              hipStream_t stream) {
  const float* x      = (const float*)d_in[0];
  const int*   batch  = (const int*)d_in[1];
  const int*   stroke = (const int*)d_in[2];
  const float* Wmax   = (const float*)d_in[3];
  const float* g_max  = (const float*)d_in[5];
  const float* be_max = (const float*)d_in[6];
  const float* Wsk    = (const float*)d_in[7];
  const float* g_sk   = (const float*)d_in[9];
  const float* be_sk  = (const float*)d_in[10];
  unsigned char* ws = (unsigned char*)d_ws;
  float* out = (float*)d_out;

  k_init <<<2048, 512, 0, stream>>>(Wmax, Wsk, ws);
  k_pass1<<<1024, 512, 0, stream>>>(x, batch, stroke, ws);
  k_out  <<<2048, 256, 0, stream>>>(batch, stroke, g_max, be_max, g_sk, be_sk, ws, out);
}